// Round 6
// baseline (281.155 us; speedup 1.0000x reference)
//
#include <hip/hip_runtime.h>
#include <hip/hip_bf16.h>

#define SIZE 128
#define NBLOCKS 4096

// var = e^b + 1/s, s = e^{-a} + e^{-lv};  inv_var = s/(e^b*s+1);
// sum(logvar) over a group = -log(prod inv_var)   [range-safe for groups of 4]
__device__ __forceinline__ void body4(float4 m, float4 lv, float4 tg,
                                      const float* __restrict__ ena,
                                      const float* __restrict__ eb,
                                      float& acc) {
    float prod = 1.0f;
    #pragma unroll
    for (int k = 0; k < 4; ++k) {
        float d   = (&m.x)[k] - (&tg.x)[k];
        float t   = __expf(-(&lv.x)[k]);               // v_exp_f32
        float s   = ena[k] + t;
        float u   = __builtin_fmaf(eb[k], s, 1.0f);
        float inv = s * __builtin_amdgcn_rcpf(u);      // v_rcp_f32
        acc  += d * d * inv;
        prod *= inv;
    }
    acc -= __logf(prod);                               // one log per 4 elems
}

__global__ __launch_bounds__(256) void probloss_fused(
    const float4* __restrict__ inputs,    // (N, 256): 64 float4/row
    const float4* __restrict__ targets,   // (N, 128): 32 float4/row
    const float4* __restrict__ maxlv,     // 32 float4
    const float4* __restrict__ minlv,     // 32 float4
    float* __restrict__ part,             // NBLOCKS partials (d_ws)
    unsigned* __restrict__ counter,       // arrival counter (d_ws), memset 0
    float* __restrict__ out,
    int nrows)
{
    const int gtid    = blockIdx.x * blockDim.x + threadIdx.x;
    const int cg      = gtid & 31;        // fixed column group
    const int row0    = gtid >> 5;
    const int rstride = (gridDim.x * blockDim.x) >> 5;   // 32768 -> 8 iters

    float4 a = maxlv[cg];
    float4 b = minlv[cg];
    float ena[4], eb[4];
    #pragma unroll
    for (int k = 0; k < 4; ++k) {
        ena[k] = __expf(-(&a.x)[k]);
        eb[k]  = __expf((&b.x)[k]);
    }

    float acc = 0.0f;
    for (int r = row0; r < nrows; r += rstride) {
        body4(inputs[r * 64 + cg], inputs[r * 64 + 32 + cg],
              targets[r * 32 + cg], ena, eb, acc);
    }

    // Wave-64 reduction
    #pragma unroll
    for (int off = 32; off > 0; off >>= 1)
        acc += __shfl_down(acc, off);

    __shared__ float smem[4];
    __shared__ bool amLast;
    const int lane = threadIdx.x & 63;
    const int wid  = threadIdx.x >> 6;
    if (lane == 0) smem[wid] = acc;
    __syncthreads();
    if (threadIdx.x == 0) {
        part[blockIdx.x] = smem[0] + smem[1] + smem[2] + smem[3];
        __threadfence();                               // release (device scope)
        unsigned prev = atomicAdd(counter, 1u);
        amLast = (prev == (unsigned)(gridDim.x - 1));
    }
    __syncthreads();

    if (amLast) {
        __threadfence();                               // acquire (device scope)
        float facc = 0.0f;
        for (int i = threadIdx.x; i < NBLOCKS; i += 256)
            facc += part[i];
        #pragma unroll
        for (int off = 32; off > 0; off >>= 1)
            facc += __shfl_down(facc, off);
        if (lane == 0) smem[wid] = facc;
        __syncthreads();
        if (threadIdx.x == 0)
            out[0] = smem[0] + smem[1] + smem[2] + smem[3];
    }
}

extern "C" void kernel_launch(void* const* d_in, const int* in_sizes, int n_in,
                              void* d_out, int out_size, void* d_ws, size_t ws_size,
                              hipStream_t stream) {
    const float4* inputs  = (const float4*)d_in[0];
    const float4* targets = (const float4*)d_in[1];
    const float4* maxlv   = (const float4*)d_in[2];
    const float4* minlv   = (const float4*)d_in[3];
    float* out      = (float*)d_out;
    float* part     = (float*)d_ws;
    unsigned* counter = (unsigned*)((char*)d_ws + NBLOCKS * sizeof(float));

    const int nrows = in_sizes[1] / SIZE;      // N = 262144

    hipMemsetAsync(counter, 0, sizeof(unsigned), stream);
    probloss_fused<<<NBLOCKS, 256, 0, stream>>>(inputs, targets, maxlv, minlv,
                                                part, counter, out, nrows);
}

// Round 8
// 64.937 us; speedup vs baseline: 4.3296x; 4.3296x over previous
//
#include <hip/hip_runtime.h>
#include <hip/hip_bf16.h>

#define SIZE 128
#define NBLOCKS 2048

typedef float f4 __attribute__((ext_vector_type(4)));

__device__ __forceinline__ f4 ntld(const f4* __restrict__ p) {
    return __builtin_nontemporal_load(p);
}

// var = e^b + 1/s, s = e^{-a} + e^{-lv};  inv_var = s/(e^b*s+1);
// logvar contribution batched: acc -= log(prod inv_var) once per 8 elems.
__device__ __forceinline__ void acc4(f4 m, f4 lv, f4 tg,
                                     const float* __restrict__ ena,
                                     const float* __restrict__ eb,
                                     float& acc, float& prod) {
    #pragma unroll
    for (int k = 0; k < 4; ++k) {
        float d   = m[k] - tg[k];
        float t   = __expf(-lv[k]);                    // v_exp_f32
        float s   = ena[k] + t;
        float u   = __builtin_fmaf(eb[k], s, 1.0f);
        float inv = s * __builtin_amdgcn_rcpf(u);      // v_rcp_f32
        acc  += d * d * inv;
        prod *= inv;
    }
}

__global__ __launch_bounds__(256) void probloss_partial(
    const f4* __restrict__ inputs,    // (N, 256): 64 f4/row
    const f4* __restrict__ targets,   // (N, 128): 32 f4/row
    const f4* __restrict__ maxlv,     // 32 f4
    const f4* __restrict__ minlv,     // 32 f4
    float* __restrict__ part,         // NBLOCKS partials
    int nrows)
{
    const int gtid    = blockIdx.x * blockDim.x + threadIdx.x;
    const int cg      = gtid & 15;        // thread owns col-groups cg and cg+16
    const int row0    = gtid >> 4;
    const int rstride = (gridDim.x * blockDim.x) >> 4;   // 32768 -> 8 iters

    // Hoisted per-column constants for both owned groups
    f4 a0 = maxlv[cg], a1 = maxlv[cg + 16];
    f4 b0 = minlv[cg], b1 = minlv[cg + 16];
    float ena[8], eb[8];
    #pragma unroll
    for (int k = 0; k < 4; ++k) {
        ena[k]     = __expf(-a0[k]);
        ena[k + 4] = __expf(-a1[k]);
        eb[k]      = __expf(b0[k]);
        eb[k + 4]  = __expf(b1[k]);
    }

    float acc = 0.0f;
    for (int r = row0; r < nrows; r += rstride) {
        const f4* rowm = inputs  + r * 64;
        const f4* rowt = targets + r * 32;
        // 6 independent dense 16B loads per thread = 32B/lane/stream
        f4 m0 = ntld(rowm + cg);
        f4 m1 = ntld(rowm + cg + 16);
        f4 l0 = ntld(rowm + 32 + cg);
        f4 l1 = ntld(rowm + 48 + cg);
        f4 t0 = ntld(rowt + cg);
        f4 t1 = ntld(rowt + cg + 16);

        float prod = 1.0f;
        acc4(m0, l0, t0, ena,     eb,     acc, prod);
        acc4(m1, l1, t1, ena + 4, eb + 4, acc, prod);
        acc -= __logf(prod);                           // one log per 8 elems
    }

    // Wave-64 reduction
    #pragma unroll
    for (int off = 32; off > 0; off >>= 1)
        acc += __shfl_down(acc, off);

    __shared__ float smem[4];
    const int lane = threadIdx.x & 63;
    const int wid  = threadIdx.x >> 6;
    if (lane == 0) smem[wid] = acc;
    __syncthreads();
    if (threadIdx.x == 0)
        part[blockIdx.x] = smem[0] + smem[1] + smem[2] + smem[3];
}

__global__ __launch_bounds__(256) void probloss_final(
    const f4* __restrict__ part, float* __restrict__ out)
{
    float acc = 0.0f;
    for (int i = threadIdx.x; i < NBLOCKS / 4; i += 256) {
        f4 v = part[i];
        acc += (v[0] + v[1]) + (v[2] + v[3]);
    }
    #pragma unroll
    for (int off = 32; off > 0; off >>= 1)
        acc += __shfl_down(acc, off);

    __shared__ float smem[4];
    const int lane = threadIdx.x & 63;
    const int wid  = threadIdx.x >> 6;
    if (lane == 0) smem[wid] = acc;
    __syncthreads();
    if (threadIdx.x == 0)
        out[0] = smem[0] + smem[1] + smem[2] + smem[3];
}

extern "C" void kernel_launch(void* const* d_in, const int* in_sizes, int n_in,
                              void* d_out, int out_size, void* d_ws, size_t ws_size,
                              hipStream_t stream) {
    const f4* inputs  = (const f4*)d_in[0];
    const f4* targets = (const f4*)d_in[1];
    const f4* maxlv   = (const f4*)d_in[2];
    const f4* minlv   = (const f4*)d_in[3];
    float* out  = (float*)d_out;
    float* part = (float*)d_ws;

    const int nrows = in_sizes[1] / SIZE;      // N = 262144

    probloss_partial<<<NBLOCKS, 256, 0, stream>>>(inputs, targets, maxlv, minlv,
                                                  part, nrows);
    probloss_final<<<1, 256, 0, stream>>>((const f4*)part, out);
}

// Round 9
// 64.804 us; speedup vs baseline: 4.3385x; 1.0021x over previous
//
#include <hip/hip_runtime.h>
#include <hip/hip_bf16.h>

#define SIZE 128
#define NBLOCKS 2048

typedef float f4 __attribute__((ext_vector_type(4)));

__device__ __forceinline__ f4 ntld(const f4* __restrict__ p) {
    return __builtin_nontemporal_load(p);
}

// var = e^b + 1/s, s = e^{-a} + e^{-lv};  inv_var = s/(e^b*s+1);
// logvar contribution batched: acc -= log(prod inv_var) once per 8 elems.
__device__ __forceinline__ void acc4(f4 m, f4 lv, f4 tg,
                                     const float* __restrict__ ena,
                                     const float* __restrict__ eb,
                                     float& acc, float& prod) {
    #pragma unroll
    for (int k = 0; k < 4; ++k) {
        float d   = m[k] - tg[k];
        float t   = __expf(-lv[k]);                    // v_exp_f32
        float s   = ena[k] + t;
        float u   = __builtin_fmaf(eb[k], s, 1.0f);
        float inv = s * __builtin_amdgcn_rcpf(u);      // v_rcp_f32
        acc  += d * d * inv;
        prod *= inv;
    }
}

__global__ __launch_bounds__(256) void probloss_partial(
    const f4* __restrict__ inputs,    // (N, 256): 64 f4/row
    const f4* __restrict__ targets,   // (N, 128): 32 f4/row
    const f4* __restrict__ maxlv,     // 32 f4
    const f4* __restrict__ minlv,     // 32 f4
    float* __restrict__ part,         // NBLOCKS partials
    int nrows)
{
    const int gtid    = blockIdx.x * blockDim.x + threadIdx.x;
    const int cg      = gtid & 15;        // thread owns col-groups cg and cg+16
    const int row0    = gtid >> 4;
    const int rstride = (gridDim.x * blockDim.x) >> 4;   // 32768 -> 8 rows/thread

    // Hoisted per-column constants for both owned groups
    f4 a0 = maxlv[cg], a1 = maxlv[cg + 16];
    f4 b0 = minlv[cg], b1 = minlv[cg + 16];
    float ena[8], eb[8];
    #pragma unroll
    for (int k = 0; k < 4; ++k) {
        ena[k]     = __expf(-a0[k]);
        ena[k + 4] = __expf(-a1[k]);
        eb[k]      = __expf(b0[k]);
        eb[k + 4]  = __expf(b1[k]);
    }

    float accA = 0.0f, accB = 0.0f;
    // 2 rows/iter: 12 independent dense 16B nt loads in flight (192B/thread/iter)
    for (int r = row0; r < nrows; r += 2 * rstride) {
        const int r2 = r + rstride;            // nrows/rstride = 8 (even) -> r2 valid
        const f4* rowmA = inputs  + r  * 64;
        const f4* rowtA = targets + r  * 32;
        const f4* rowmB = inputs  + r2 * 64;
        const f4* rowtB = targets + r2 * 32;

        f4 mA0 = ntld(rowmA + cg);
        f4 mA1 = ntld(rowmA + cg + 16);
        f4 lA0 = ntld(rowmA + 32 + cg);
        f4 lA1 = ntld(rowmA + 48 + cg);
        f4 tA0 = ntld(rowtA + cg);
        f4 tA1 = ntld(rowtA + cg + 16);
        f4 mB0 = ntld(rowmB + cg);
        f4 mB1 = ntld(rowmB + cg + 16);
        f4 lB0 = ntld(rowmB + 32 + cg);
        f4 lB1 = ntld(rowmB + 48 + cg);
        f4 tB0 = ntld(rowtB + cg);
        f4 tB1 = ntld(rowtB + cg + 16);

        float prodA = 1.0f, prodB = 1.0f;
        acc4(mA0, lA0, tA0, ena,     eb,     accA, prodA);
        acc4(mA1, lA1, tA1, ena + 4, eb + 4, accA, prodA);
        accA -= __logf(prodA);
        acc4(mB0, lB0, tB0, ena,     eb,     accB, prodB);
        acc4(mB1, lB1, tB1, ena + 4, eb + 4, accB, prodB);
        accB -= __logf(prodB);
    }
    float acc = accA + accB;

    // Wave-64 reduction
    #pragma unroll
    for (int off = 32; off > 0; off >>= 1)
        acc += __shfl_down(acc, off);

    __shared__ float smem[4];
    const int lane = threadIdx.x & 63;
    const int wid  = threadIdx.x >> 6;
    if (lane == 0) smem[wid] = acc;
    __syncthreads();
    if (threadIdx.x == 0)
        part[blockIdx.x] = smem[0] + smem[1] + smem[2] + smem[3];
}

__global__ __launch_bounds__(256) void probloss_final(
    const f4* __restrict__ part, float* __restrict__ out)
{
    float acc = 0.0f;
    for (int i = threadIdx.x; i < NBLOCKS / 4; i += 256) {
        f4 v = part[i];
        acc += (v[0] + v[1]) + (v[2] + v[3]);
    }
    #pragma unroll
    for (int off = 32; off > 0; off >>= 1)
        acc += __shfl_down(acc, off);

    __shared__ float smem[4];
    const int lane = threadIdx.x & 63;
    const int wid  = threadIdx.x >> 6;
    if (lane == 0) smem[wid] = acc;
    __syncthreads();
    if (threadIdx.x == 0)
        out[0] = smem[0] + smem[1] + smem[2] + smem[3];
}

extern "C" void kernel_launch(void* const* d_in, const int* in_sizes, int n_in,
                              void* d_out, int out_size, void* d_ws, size_t ws_size,
                              hipStream_t stream) {
    const f4* inputs  = (const f4*)d_in[0];
    const f4* targets = (const f4*)d_in[1];
    const f4* maxlv   = (const f4*)d_in[2];
    const f4* minlv   = (const f4*)d_in[3];
    float* out  = (float*)d_out;
    float* part = (float*)d_ws;

    const int nrows = in_sizes[1] / SIZE;      // N = 262144

    probloss_partial<<<NBLOCKS, 256, 0, stream>>>(inputs, targets, maxlv, minlv,
                                                  part, nrows);
    probloss_final<<<1, 256, 0, stream>>>((const f4*)part, out);
}